// Round 5
// baseline (38.015 us; speedup 1.0000x reference)
//
#include <hip/hip_runtime.h>
#include <hip/hip_bf16.h>

// ARD kernel matrix: out[i][j] = exp(-0.5 * sum_d (x[i][d]-y[j][d])^2 / exp(lbw[d]))
// Quadratic expansion: weight rows by exp(-0.5*lbw), cast bf16, MFMA GEMM for the
// cross term, fused epilogue exp(-0.5*(x2+y2-2*cross)).
//
// Round 5: attack the WRITE path. Direct fragment stores are 64B-per-row
// segments at 16KB stride (~2.2 TB/s effective). New: LDS-transpose epilogue —
// exp'd tile staged in LDS (float[128][132], +4 pad), then linear stores where
// 32 consecutive lanes write one 512B-contiguous row segment. Compute side:
// R4's verified staging/swizzle/frags, 4 waves of 64x64 (halves LDS traffic).

typedef __attribute__((ext_vector_type(8))) short bf16x8;   // 8 bf16 = 4 VGPRs
typedef __attribute__((ext_vector_type(4))) float f32x4;    // MFMA accumulator

#define NN 4096
#define MM 4096
#define DD 256

#define BM 128
#define BN 128
#define HK 128           // half of K
#define EPLD 132         // epilogue LDS row stride in floats (128 + 4 pad)

#define GLOAD16(gp, lp)                                                        \
    __builtin_amdgcn_global_load_lds(                                          \
        (const __attribute__((address_space(1))) void*)(gp),                   \
        (__attribute__((address_space(3))) void*)(lp), 16, 0, 0)

// ---------------------------------------------------------------------------
// prep: one wave per row (x rows then y rows). Scale by exp(-0.5*lbw), cast
// bf16, accumulate row norm from the ROUNDED values (keeps pdist >= 0).
// ---------------------------------------------------------------------------
__global__ __launch_bounds__(256) void ard_prep(
    const float* __restrict__ x, const float* __restrict__ y,
    const float* __restrict__ lbw,
    __hip_bfloat16* __restrict__ xw, __hip_bfloat16* __restrict__ yw,
    float* __restrict__ x2, float* __restrict__ y2)
{
    const int lane = threadIdx.x & 63;
    const int row  = blockIdx.x * 4 + (threadIdx.x >> 6);   // 0 .. N+M-1

    const float* src;
    __hip_bfloat16* dst;
    float* nrm;
    if (row < NN) {
        src = x + (size_t)row * DD;
        dst = xw + (size_t)row * DD;
        nrm = x2 + row;
    } else {
        const int r = row - NN;
        src = y + (size_t)r * DD;
        dst = yw + (size_t)r * DD;
        nrm = y2 + r;
    }

    const float4 v  = reinterpret_cast<const float4*>(src)[lane];
    const float4 lw = reinterpret_cast<const float4*>(lbw)[lane];

    float wv[4];
    wv[0] = v.x * __expf(-0.5f * lw.x);
    wv[1] = v.y * __expf(-0.5f * lw.y);
    wv[2] = v.z * __expf(-0.5f * lw.z);
    wv[3] = v.w * __expf(-0.5f * lw.w);

    __hip_bfloat16 h[4];
    float s = 0.0f;
#pragma unroll
    for (int j = 0; j < 4; ++j) {
        h[j] = __float2bfloat16(wv[j]);
        const float f = __bfloat162float(h[j]);
        s += f * f;
    }

    reinterpret_cast<uint2*>(dst)[lane] = *reinterpret_cast<uint2*>(h);

#pragma unroll
    for (int off = 32; off > 0; off >>= 1) s += __shfl_down(s, off);
    if (lane == 0) *nrm = s;
}

// ---------------------------------------------------------------------------
// GEMM + LDS-transposed epilogue. 4 waves in 2x2; wave owns 64x64 output as
// 4x4 frags of mfma_f32_16x16x32_bf16 with OPERANDS SWAPPED (b_frag in slot A):
//   D "col" index (lane&15)        -> output ROW (xw row)
//   D "row" index ((lane>>4)*4+reg) -> output COL (yw row), 4 consecutive cols.
//
// LDS compute phase: per operand, two half-K buffers [128 rows][256 B];
// logical byte-col c of row r lives at r*256 + (c ^ ((r&7)<<4)); swizzle
// applied on the GLOBAL source address (rule #21), LDS dest linear.
// LDS epilogue phase (aliased over sA after barrier): float[128][EPLD].
// ---------------------------------------------------------------------------
__global__ __launch_bounds__(256) void ard_gemm(
    const __hip_bfloat16* __restrict__ A,   // xw [N][D]
    const __hip_bfloat16* __restrict__ B,   // yw [M][D]
    const float* __restrict__ x2, const float* __restrict__ y2,
    float* __restrict__ out)                // [N][M]
{
    __shared__ __align__(16) char smem[131072];   // 128 KB
    // carve: sA halves at 0 / 32K, sB halves at 64K / 96K; ep aliases [0,67.6K)
    char* sAh[2] = { smem,         smem + 32768 };
    char* sBh[2] = { smem + 65536, smem + 98304 };
    float* ep = reinterpret_cast<float*>(smem);

    const int tid  = threadIdx.x;
    const int lane = tid & 63;
    const int wid  = tid >> 6;     // 0..3
    const int wr   = wid >> 1;     // 0..1  (64-row band)
    const int wc   = wid & 1;      // 0..1  (64-col band)

    const int bi = blockIdx.y;
    const int bj = blockIdx.x;
    const size_t arow0 = (size_t)bi * BM;
    const size_t brow0 = (size_t)bj * BN;

    // staging: one GLOAD16 = 1 KB = 4 rows x 256 B. lane -> row r0+(lane>>4),
    // 16B slot lane&15. Wave w stages rows [w*32, w*32+32) of each buffer.
    const int crow = lane >> 4;          // 0..3 row within chunk
    const int slot = lane & 15;          // 16B slot within 256B row

    auto stage = [&](int h) {
        const int colb = h * 256;        // global byte-col base of this half
#pragma unroll
        for (int t = 0; t < 8; ++t) {
            const int r   = wid * 32 + t * 4;                 // wave-uniform
            const int row = r + crow;                         // per-lane
            const int lcb = colb + ((slot * 16) ^ ((row & 7) << 4));
            GLOAD16((const char*)(A + (arow0 + row) * DD) + lcb, sAh[h] + r * 256);
            GLOAD16((const char*)(B + (brow0 + row) * DD) + lcb, sBh[h] + r * 256);
        }
    };

    f32x4 acc[4][4] = {};
    const int frow = lane & 15;          // fragment row within 16
    const int fkb  = (lane >> 4) * 16;   // K byte sub-offset
    const int swz  = (frow & 7) << 4;    // row&7 == frow&7 (row bases %8==0)

    stage(0);
    __syncthreads();          // h0 staged (drains vmcnt)
    stage(1);                 // h1 loads fly under h0 compute

#pragma unroll
    for (int h = 0; h < 2; ++h) {
        if (h == 1) __syncthreads();     // h1 staged
#pragma unroll
        for (int kk = 0; kk < 4; ++kk) {
            const int kb = kk * 64 + fkb;
            bf16x8 a[4], b[4];
#pragma unroll
            for (int m = 0; m < 4; ++m) {
                const int row = wr * 64 + m * 16 + frow;
                a[m] = *reinterpret_cast<const bf16x8*>(sAh[h] + row * 256 + (kb ^ swz));
            }
#pragma unroll
            for (int n = 0; n < 4; ++n) {
                const int row = wc * 64 + n * 16 + frow;
                b[n] = *reinterpret_cast<const bf16x8*>(sBh[h] + row * 256 + (kb ^ swz));
            }
#pragma unroll
            for (int m = 0; m < 4; ++m)
#pragma unroll
                for (int n = 0; n < 4; ++n)
                    acc[m][n] = __builtin_amdgcn_mfma_f32_16x16x32_bf16(
                        b[n], a[m], acc[m][n], 0, 0, 0);   // SWAPPED
        }
    }

    __syncthreads();   // all LDS reads done before ep overwrites sA

    // ---- epilogue compute + LDS transpose staging -------------------------
    // out row (local) = wr*64 + m*16 + (lane&15); cols = wc*64 + n*16 + rsub+j
    const int cl   = lane & 15;
    const int rsub = (lane >> 4) * 4;
    const int row0 = bi * BM;
    const int col0 = bj * BN;

#pragma unroll
    for (int m = 0; m < 4; ++m) {
        const int rl = wr * 64 + m * 16 + cl;
        const float xv = x2[row0 + rl];
#pragma unroll
        for (int n = 0; n < 4; ++n) {
            const int c = wc * 64 + n * 16 + rsub;
            const float4 yv = *reinterpret_cast<const float4*>(y2 + col0 + c);
            f32x4 o;
            o.x = __expf(-0.5f * fmaxf(xv + yv.x - 2.0f * acc[m][n][0], 0.0f));
            o.y = __expf(-0.5f * fmaxf(xv + yv.y - 2.0f * acc[m][n][1], 0.0f));
            o.z = __expf(-0.5f * fmaxf(xv + yv.z - 2.0f * acc[m][n][2], 0.0f));
            o.w = __expf(-0.5f * fmaxf(xv + yv.w - 2.0f * acc[m][n][3], 0.0f));
            *reinterpret_cast<f32x4*>(&ep[rl * EPLD + c]) = o;
        }
    }

    __syncthreads();   // tile fully staged in ep

    // ---- linear stores: 32 consecutive lanes = one 512B row segment -------
    // per iter: 256 threads x 16 B = 8 rows; 16 iters cover 128 rows.
    const int srow2 = tid >> 5;          // 0..7
    const int cfl   = (tid & 31) * 4;    // float col 0..124
#pragma unroll
    for (int i = 0; i < 16; ++i) {
        const int row = i * 8 + srow2;
        const f32x4 v = *reinterpret_cast<const f32x4*>(&ep[row * EPLD + cfl]);
        __builtin_nontemporal_store(
            v, reinterpret_cast<f32x4*>(out + (size_t)(row0 + row) * MM + col0 + cfl));
    }
}

extern "C" void kernel_launch(void* const* d_in, const int* in_sizes, int n_in,
                              void* d_out, int out_size, void* d_ws, size_t ws_size,
                              hipStream_t stream) {
    const float* x   = (const float*)d_in[0];
    const float* y   = (const float*)d_in[1];
    const float* lbw = (const float*)d_in[2];
    float* out = (float*)d_out;

    char* ws = (char*)d_ws;
    __hip_bfloat16* xw = (__hip_bfloat16*)ws;                             // 2 MB
    __hip_bfloat16* yw = (__hip_bfloat16*)(ws + (size_t)2 * 1024 * 1024); // 2 MB
    float* x2 = (float*)(ws + (size_t)4 * 1024 * 1024);                   // 16 KB
    float* y2 = (float*)(ws + (size_t)4 * 1024 * 1024 + 16384);           // 16 KB

    ard_prep<<<(NN + MM) / 4, 256, 0, stream>>>(x, y, lbw, xw, yw, x2, y2);

    dim3 grid(MM / BN, NN / BM);
    ard_gemm<<<grid, 256, 0, stream>>>(xw, yw, x2, y2, out);
}

// Round 6
// 37.377 us; speedup vs baseline: 1.0171x; 1.0171x over previous
//
#include <hip/hip_runtime.h>
#include <hip/hip_bf16.h>

// ARD kernel matrix: out[i][j] = exp(-0.5 * sum_d (x[i][d]-y[j][d])^2 / exp(lbw[d]))
// Quadratic expansion: weight rows by exp(-0.5*lbw), cast bf16, MFMA GEMM for the
// cross term, fused epilogue exp(-0.5*(x2+y2-2*cross)).
//
// Round 6: OCCUPANCY. R5 counters showed gemm=42.8us at 1.57 TB/s with 1
// block/CU (128 KB LDS) — serialization wall, not write path. New: m97-style
// 32 KB/block (BK=32 double-buffered), 4 waves, ~3 blocks/CU co-resident so
// staging/compute/store phases of different blocks overlap. Keeps verified
// swapped-operand frag algebra + direct f32x4 stores (plain, L2-coalesced).

typedef __attribute__((ext_vector_type(8))) short bf16x8;   // 8 bf16 = 4 VGPRs
typedef __attribute__((ext_vector_type(4))) float f32x4;    // MFMA accumulator

#define NN 4096
#define MM 4096
#define DD 256

#define BM 128
#define BN 128
#define BK 32            // K-step; 64 B per LDS row
#define NKT (DD / BK)    // 8

#define GLOAD16(gp, lp)                                                        \
    __builtin_amdgcn_global_load_lds(                                          \
        (const __attribute__((address_space(1))) void*)(gp),                   \
        (__attribute__((address_space(3))) void*)(lp), 16, 0, 0)

// ---------------------------------------------------------------------------
// prep: one wave per row (x rows then y rows). Scale by exp(-0.5*lbw), cast
// bf16, accumulate row norm from the ROUNDED values (keeps pdist >= 0).
// ---------------------------------------------------------------------------
__global__ __launch_bounds__(256) void ard_prep(
    const float* __restrict__ x, const float* __restrict__ y,
    const float* __restrict__ lbw,
    __hip_bfloat16* __restrict__ xw, __hip_bfloat16* __restrict__ yw,
    float* __restrict__ x2, float* __restrict__ y2)
{
    const int lane = threadIdx.x & 63;
    const int row  = blockIdx.x * 4 + (threadIdx.x >> 6);   // 0 .. N+M-1

    const float* src;
    __hip_bfloat16* dst;
    float* nrm;
    if (row < NN) {
        src = x + (size_t)row * DD;
        dst = xw + (size_t)row * DD;
        nrm = x2 + row;
    } else {
        const int r = row - NN;
        src = y + (size_t)r * DD;
        dst = yw + (size_t)r * DD;
        nrm = y2 + r;
    }

    const float4 v  = reinterpret_cast<const float4*>(src)[lane];
    const float4 lw = reinterpret_cast<const float4*>(lbw)[lane];

    float wv[4];
    wv[0] = v.x * __expf(-0.5f * lw.x);
    wv[1] = v.y * __expf(-0.5f * lw.y);
    wv[2] = v.z * __expf(-0.5f * lw.z);
    wv[3] = v.w * __expf(-0.5f * lw.w);

    __hip_bfloat16 h[4];
    float s = 0.0f;
#pragma unroll
    for (int j = 0; j < 4; ++j) {
        h[j] = __float2bfloat16(wv[j]);
        const float f = __bfloat162float(h[j]);
        s += f * f;
    }

    reinterpret_cast<uint2*>(dst)[lane] = *reinterpret_cast<uint2*>(h);

#pragma unroll
    for (int off = 32; off > 0; off >>= 1) s += __shfl_down(s, off);
    if (lane == 0) *nrm = s;
}

// ---------------------------------------------------------------------------
// GEMM + fused epilogue. 4 waves in 2x2; wave owns 64x64 output as 4x4 frags
// of mfma_f32_16x16x32_bf16 with OPERANDS SWAPPED (b_frag in slot A):
//   D "col" index (lane&15)         -> output ROW (xw row)
//   D "row" index ((lane>>4)*4+reg) -> output COL (yw row), 4 consecutive cols.
//
// LDS: per operand, double-buffered [128 rows][64 B]; logical byte-col c of
// row r lives at r*64 + (c ^ ((r&3)<<4)). global_load_lds writes linearly, so
// the swizzle is applied on the per-lane GLOBAL source address (rule #21).
// Bank audit for ds_read_b128 (64 lanes x 16 B = 8 accesses/bank minimum):
// phys mod 128 = (row&1)<<6 | ((fkb4 ^ (row&3))<<4) -> each 16B slot gets
// exactly 8 lanes => conflict-free.
// ---------------------------------------------------------------------------
__global__ __launch_bounds__(256) void ard_gemm(
    const __hip_bfloat16* __restrict__ A,   // xw [N][D]
    const __hip_bfloat16* __restrict__ B,   // yw [M][D]
    const float* __restrict__ x2, const float* __restrict__ y2,
    float* __restrict__ out)                // [N][M]
{
    __shared__ __align__(16) char sAb[2][BM * BK * 2];   // 2 x 8 KB
    __shared__ __align__(16) char sBb[2][BN * BK * 2];   // 2 x 8 KB

    const int tid  = threadIdx.x;
    const int lane = tid & 63;
    const int wid  = tid >> 6;     // 0..3
    const int wr   = wid >> 1;     // 0..1  (64-row band)
    const int wc   = wid & 1;      // 0..1  (64-col band)

    const int bi = blockIdx.y;
    const int bj = blockIdx.x;
    const size_t arow0 = (size_t)bi * BM;
    const size_t brow0 = (size_t)bj * BN;

    // staging: one GLOAD16 = 1 KB = 16 rows x 64 B. lane -> row r0+(lane>>2),
    // 16B slot lane&3. Wave w stages rows [w*32, w*32+32): 2 gloads per operand.
    const int crow = lane >> 2;          // 0..15 row within chunk
    const int slot = lane & 3;           // 16B slot within 64B row

    auto stage = [&](int buf, int kt) {
        const int colb = kt * 64;        // global byte-col base of this K-step
        const int lcb  = colb + ((slot * 16) ^ ((crow & 3) << 4));
#pragma unroll
        for (int t = 0; t < 2; ++t) {
            const int r   = wid * 32 + t * 16;                // wave-uniform
            const int row = r + crow;                         // per-lane
            GLOAD16((const char*)(A + (arow0 + row) * DD) + lcb, sAb[buf] + r * 64);
            GLOAD16((const char*)(B + (brow0 + row) * DD) + lcb, sBb[buf] + r * 64);
        }
    };

    f32x4 acc[4][4] = {};
    const int frow = lane & 15;          // fragment row within 16
    const int fkb  = (lane >> 4) * 16;   // K byte sub-offset within 64B row
    const int swz  = (frow & 3) << 4;    // row&3 == frow&3 (row bases %16==0)
    const int rdo  = fkb ^ swz;          // per-lane byte offset within row

    stage(0, 0);
    __syncthreads();   // buf0 staged (vmcnt drained by barrier semantics)

#pragma unroll
    for (int kt = 0; kt < NKT; ++kt) {
        const int cur = kt & 1;
        if (kt + 1 < NKT) stage(cur ^ 1, kt + 1);   // prefetch flies under MFMA

        bf16x8 a[4], b[4];
#pragma unroll
        for (int m = 0; m < 4; ++m) {
            const int row = wr * 64 + m * 16 + frow;
            a[m] = *reinterpret_cast<const bf16x8*>(sAb[cur] + row * 64 + rdo);
        }
#pragma unroll
        for (int n = 0; n < 4; ++n) {
            const int row = wc * 64 + n * 16 + frow;
            b[n] = *reinterpret_cast<const bf16x8*>(sBb[cur] + row * 64 + rdo);
        }
#pragma unroll
        for (int m = 0; m < 4; ++m)
#pragma unroll
            for (int n = 0; n < 4; ++n)
                acc[m][n] = __builtin_amdgcn_mfma_f32_16x16x32_bf16(
                    b[n], a[m], acc[m][n], 0, 0, 0);   // SWAPPED

        __syncthreads();   // next buf staged; cur consumed before overwrite
    }

    // epilogue: out row = row0 + m*16 + (lane&15); cols = col0 + n*16 + rsub+j
    const int row0 = bi * BM + wr * 64;
    const int col0 = bj * BN + wc * 64;
    const int cl   = lane & 15;
    const int rsub = (lane >> 4) * 4;

#pragma unroll
    for (int m = 0; m < 4; ++m) {
        const int r = row0 + m * 16 + cl;
        const float xv = x2[r];
        float* orow = out + (size_t)r * MM;
#pragma unroll
        for (int n = 0; n < 4; ++n) {
            const int c = col0 + n * 16 + rsub;
            const float4 yv = *reinterpret_cast<const float4*>(y2 + c);
            f32x4 o;
            o.x = __expf(-0.5f * fmaxf(xv + yv.x - 2.0f * acc[m][n][0], 0.0f));
            o.y = __expf(-0.5f * fmaxf(xv + yv.y - 2.0f * acc[m][n][1], 0.0f));
            o.z = __expf(-0.5f * fmaxf(xv + yv.z - 2.0f * acc[m][n][2], 0.0f));
            o.w = __expf(-0.5f * fmaxf(xv + yv.w - 2.0f * acc[m][n][3], 0.0f));
            *reinterpret_cast<f32x4*>(orow + c) = o;   // plain store: L2 coalesces
        }
    }
}

extern "C" void kernel_launch(void* const* d_in, const int* in_sizes, int n_in,
                              void* d_out, int out_size, void* d_ws, size_t ws_size,
                              hipStream_t stream) {
    const float* x   = (const float*)d_in[0];
    const float* y   = (const float*)d_in[1];
    const float* lbw = (const float*)d_in[2];
    float* out = (float*)d_out;

    char* ws = (char*)d_ws;
    __hip_bfloat16* xw = (__hip_bfloat16*)ws;                             // 2 MB
    __hip_bfloat16* yw = (__hip_bfloat16*)(ws + (size_t)2 * 1024 * 1024); // 2 MB
    float* x2 = (float*)(ws + (size_t)4 * 1024 * 1024);                   // 16 KB
    float* y2 = (float*)(ws + (size_t)4 * 1024 * 1024 + 16384);           // 16 KB

    ard_prep<<<(NN + MM) / 4, 256, 0, stream>>>(x, y, lbw, xw, yw, x2, y2);

    dim3 grid(MM / BN, NN / BM);
    ard_gemm<<<grid, 256, 0, stream>>>(xw, yw, x2, y2, out);
}